// Round 1
// baseline (487.754 us; speedup 1.0000x reference)
//
#include <hip/hip_runtime.h>

typedef short bf16x8 __attribute__((ext_vector_type(8)));
typedef float f32x4 __attribute__((ext_vector_type(4)));

#define MFMA16(a, b, c) __builtin_amdgcn_mfma_f32_16x16x32_bf16(a, b, c, 0, 0, 0)

constexpr int Bn = 4, Sn = 4096, En = 1024, Hn = 128;

__device__ inline unsigned short f2bf(float f) {
    unsigned int u = __builtin_bit_cast(unsigned int, f);
    u += 0x7fff + ((u >> 16) & 1);   // round-to-nearest-even
    return (unsigned short)(u >> 16);
}

// ---------------- QKV projection: y[s][h] = sum_e x[s][e] * W[h][e] ----------------
// grid (BS/128, 3), block 256 (4 waves, 2x2 of 64x64). gy: 0->q(Wq), 1->k(Wk), 2->v(Wv)
__global__ __launch_bounds__(256) void proj_kernel(
    const float* __restrict__ x,
    const float* __restrict__ Wk, const float* __restrict__ Wq, const float* __restrict__ Wv,
    unsigned short* __restrict__ qb, unsigned short* __restrict__ kb, unsigned short* __restrict__ vb)
{
    __shared__ unsigned short xs[128][40];   // stride 40 bf16 = 80B (16B-aligned rows)
    __shared__ unsigned short wsm[128][40];

    const float* W;
    unsigned short* ob;
    if (blockIdx.y == 0)      { W = Wq; ob = qb; }
    else if (blockIdx.y == 1) { W = Wk; ob = kb; }
    else                      { W = Wv; ob = vb; }

    const int m0 = blockIdx.x * 128;
    const int tid = threadIdx.x;
    const int lane = tid & 63, wave = tid >> 6;
    const int l15 = lane & 15, quad = lane >> 4;
    const int wm = (wave & 1) * 64, wn = (wave >> 1) * 64;

    f32x4 acc[4][4] = {};

    const int srow = tid >> 3;        // 0..31
    const int scol = (tid & 7) * 4;   // 0,4,...,28

    for (int kc = 0; kc < En / 32; ++kc) {
        const int k0 = kc * 32;
        for (int p = 0; p < 4; ++p) {
            int row = srow + p * 32;
            float4 xv = *(const float4*)&x[(size_t)(m0 + row) * En + k0 + scol];
            unsigned short tx[4] = { f2bf(xv.x), f2bf(xv.y), f2bf(xv.z), f2bf(xv.w) };
            *(uint2*)&xs[row][scol] = *(uint2*)tx;
            float4 wv4 = *(const float4*)&W[(size_t)row * En + k0 + scol];
            unsigned short tw[4] = { f2bf(wv4.x), f2bf(wv4.y), f2bf(wv4.z), f2bf(wv4.w) };
            *(uint2*)&wsm[row][scol] = *(uint2*)tw;
        }
        __syncthreads();
        bf16x8 af[4], bfr[4];
        for (int i = 0; i < 4; ++i) af[i]  = *(const bf16x8*)&xs[wm + i * 16 + l15][quad * 8];
        for (int j = 0; j < 4; ++j) bfr[j] = *(const bf16x8*)&wsm[wn + j * 16 + l15][quad * 8];
        for (int i = 0; i < 4; ++i)
            for (int j = 0; j < 4; ++j)
                acc[i][j] = MFMA16(af[i], bfr[j], acc[i][j]);
        __syncthreads();
    }

    // epilogue: C/D layout col=lane&15, row=quad*4+reg
    for (int i = 0; i < 4; ++i) {
        int rowb = m0 + wm + i * 16 + quad * 4;
        for (int j = 0; j < 4; ++j) {
            int col = wn + j * 16 + l15;
            for (int r = 0; r < 4; ++r)
                ob[(size_t)(rowb + r) * Hn + col] = f2bf(acc[i][j][r]);
        }
    }
}

// ---------------- flash causal attention ----------------
// grid (S/32, B), block 128 (2 waves, each owns 16 q-rows). BQ=32, BK=64.
__global__ __launch_bounds__(128) void attn_kernel(
    const unsigned short* __restrict__ qb, const unsigned short* __restrict__ kb,
    const unsigned short* __restrict__ vb, float* __restrict__ out)
{
    __shared__ unsigned short ks[64][136];  // K tile natural [key][h], pad for B-frag reads
    __shared__ unsigned short vt[128][72];  // V^T [h][key]
    __shared__ unsigned short ps[32][72];   // P strip [q][key] for A-frag reads

    const int b = blockIdx.y;
    const int qt = (int)gridDim.x - 1 - (int)blockIdx.x;  // longest blocks dispatch first
    const int q0 = qt * 32;
    const int tid = threadIdx.x;
    const int lane = tid & 63, wave = tid >> 6;
    const int l15 = lane & 15, quad = lane >> 4;

    // Q A-fragments held in registers for the whole kernel
    const unsigned short* qg = qb + (size_t)(b * Sn + q0) * Hn;
    bf16x8 qf[4];
    {
        int qrow = wave * 16 + l15;
        for (int f = 0; f < 4; ++f)
            qf[f] = *(const bf16x8*)&qg[qrow * Hn + f * 32 + quad * 8];
    }

    f32x4 o[8] = {};
    float m_r[4] = { -INFINITY, -INFINITY, -INFINITY, -INFINITY };
    float l_r[4] = { 0.f, 0.f, 0.f, 0.f };

    const float cscale = 1.44269504089f * 0.03125f;  // log2(e) * E^-0.5
    const int nkt = q0 / 64 + 1;

    for (int kt = 0; kt < nkt; ++kt) {
        const int kt0 = kt * 64;
        const unsigned short* kgp = kb + (size_t)(b * Sn + kt0) * Hn;
        const unsigned short* vgp = vb + (size_t)(b * Sn + kt0) * Hn;
        // stage K natural, V transposed
        for (int p = 0; p < 8; ++p) {
            int i = p * 128 + tid;      // 0..1023
            int row = i >> 4;           // 0..63
            int c8 = (i & 15) * 8;      // 0..120
            *(bf16x8*)&ks[row][c8] = *(const bf16x8*)&kgp[row * Hn + c8];
            bf16x8 vvv = *(const bf16x8*)&vgp[row * Hn + c8];
            for (int j = 0; j < 8; ++j) vt[c8 + j][row] = (unsigned short)vvv[j];
        }
        __syncthreads();

        // S = Q K^T (each wave: 16 rows x 64 keys), in log2 domain with E^-0.5 folded in
        float u[4][4];
        for (int nt = 0; nt < 4; ++nt) {
            f32x4 s = {};
            for (int kk = 0; kk < 4; ++kk) {
                bf16x8 kf = *(const bf16x8*)&ks[nt * 16 + l15][kk * 32 + quad * 8];
                s = MFMA16(qf[kk], kf, s);
            }
            for (int r = 0; r < 4; ++r) u[nt][r] = s[r] * cscale;
        }
        // causal mask only intersects the last k-tile
        if (kt == nkt - 1) {
            for (int nt = 0; nt < 4; ++nt) {
                int key = kt0 + nt * 16 + l15;
                for (int r = 0; r < 4; ++r) {
                    int qq = q0 + wave * 16 + quad * 4 + r;
                    if (key > qq) u[nt][r] = -INFINITY;
                }
            }
        }
        // online softmax: row r lives on the 16 lanes of this quad
        float alpha[4];
        for (int r = 0; r < 4; ++r) {
            float mx = fmaxf(fmaxf(u[0][r], u[1][r]), fmaxf(u[2][r], u[3][r]));
            for (int d = 1; d < 16; d <<= 1) mx = fmaxf(mx, __shfl_xor(mx, d, 64));
            float mn = fmaxf(m_r[r], mx);
            alpha[r] = exp2f(m_r[r] - mn);
            m_r[r] = mn;
        }
        float rs[4];
        for (int r = 0; r < 4; ++r) {
            float sum = 0.f;
            for (int nt = 0; nt < 4; ++nt) {
                float p = exp2f(u[nt][r] - m_r[r]);
                u[nt][r] = p;
                sum += p;
            }
            rs[r] = sum;
        }
        for (int r = 0; r < 4; ++r) {
            for (int d = 1; d < 16; d <<= 1) rs[r] += __shfl_xor(rs[r], d, 64);
            l_r[r] = l_r[r] * alpha[r] + rs[r];
        }
        // P -> LDS (C-layout scatter), rescale O
        for (int nt = 0; nt < 4; ++nt)
            for (int r = 0; r < 4; ++r)
                ps[wave * 16 + quad * 4 + r][nt * 16 + l15] = f2bf(u[nt][r]);
        for (int t = 0; t < 8; ++t) {
            f32x4 ot = o[t];
            for (int r = 0; r < 4; ++r) ot[r] *= alpha[r];
            o[t] = ot;
        }
        __syncthreads();
        // O += P V  (A-frags of P from LDS, B-frags of V from vt)
        for (int k2 = 0; k2 < 2; ++k2) {
            bf16x8 pf = *(const bf16x8*)&ps[wave * 16 + l15][k2 * 32 + quad * 8];
            for (int t = 0; t < 8; ++t) {
                bf16x8 vf = *(const bf16x8*)&vt[t * 16 + l15][k2 * 32 + quad * 8];
                o[t] = MFMA16(pf, vf, o[t]);
            }
        }
        __syncthreads();
    }

    float* og = out + (size_t)(b * Sn + q0) * Hn;
    for (int t = 0; t < 8; ++t) {
        for (int r = 0; r < 4; ++r) {
            int row = wave * 16 + quad * 4 + r;
            int col = t * 16 + l15;
            og[(size_t)row * Hn + col] = o[t][r] / l_r[r];
        }
    }
}

extern "C" void kernel_launch(void* const* d_in, const int* in_sizes, int n_in,
                              void* d_out, int out_size, void* d_ws, size_t ws_size,
                              hipStream_t stream)
{
    const float* x  = (const float*)d_in[0];
    const float* Wk = (const float*)d_in[1];
    const float* Wq = (const float*)d_in[2];
    const float* Wv = (const float*)d_in[3];
    float* out = (float*)d_out;

    unsigned short* qbuf = (unsigned short*)d_ws;                   // 4 MB
    unsigned short* kbuf = qbuf + (size_t)Bn * Sn * Hn;             // 4 MB
    unsigned short* vbuf = kbuf + (size_t)Bn * Sn * Hn;             // 4 MB

    proj_kernel<<<dim3(Bn * Sn / 128, 3), 256, 0, stream>>>(x, Wk, Wq, Wv, qbuf, kbuf, vbuf);
    attn_kernel<<<dim3(Sn / 32, Bn), 128, 0, stream>>>(qbuf, kbuf, vbuf, out);
}

// Round 2
// 286.205 us; speedup vs baseline: 1.7042x; 1.7042x over previous
//
#include <hip/hip_runtime.h>

typedef short bf16x8 __attribute__((ext_vector_type(8)));
typedef float f32x4 __attribute__((ext_vector_type(4)));

#define MFMA16(a, b, c) __builtin_amdgcn_mfma_f32_16x16x32_bf16(a, b, c, 0, 0, 0)

constexpr int Bn = 4, Sn = 4096, En = 1024, Hn = 128;

__device__ inline unsigned short f2bf(float f) {
    unsigned int u = __builtin_bit_cast(unsigned int, f);
    u += 0x7fff + ((u >> 16) & 1);   // round-to-nearest-even
    return (unsigned short)(u >> 16);
}

// ---------------- QKV projection ----------------
// gy 0: q[s][h] = x Wq^T   gy 1: k[s][h] = x Wk^T
// gy 2: vT[h][s] = Wv x^T  (same GEMM, A/B swapped -> output already transposed,
//                           so attention can stage V^T with clean b128 writes)
// grid (BS/128, 3), block 256 (4 waves, 2x2 of 64x64 per 128x128 tile). BK=64.
__global__ __launch_bounds__(256, 2) void proj_kernel(
    const float* __restrict__ x,
    const float* __restrict__ Wk, const float* __restrict__ Wq, const float* __restrict__ Wv,
    unsigned short* __restrict__ qb, unsigned short* __restrict__ kb,
    unsigned short* __restrict__ vbT)
{
    __shared__ unsigned short xs[128][72];    // x tile  [row 128][64 bf16 + pad]
    __shared__ unsigned short wsm[128][72];   // W tile  [h 128][64 bf16 + pad]

    const int gy = blockIdx.y;
    const float* W = (gy == 0) ? Wq : (gy == 1) ? Wk : Wv;

    const int m0 = blockIdx.x * 128;          // x-row tile base (s' for gy==2's n-dim)
    const int tid = threadIdx.x;
    const int lane = tid & 63, wave = tid >> 6;
    const int l15 = lane & 15, quad = lane >> 4;
    const int wm = (wave & 1) * 64, wn = (wave >> 1) * 64;

    f32x4 acc[4][4] = {};

    // staging: per matrix 128 rows x 64 fp32 = 2048 float4 chunks / 256 thr = 8 each
    float4 xp[8], wp[8];
    {
        for (int p = 0; p < 8; ++p) {
            int i = p * 256 + tid, row = i >> 4, c = (i & 15) * 4;
            xp[p] = *(const float4*)&x[(size_t)(m0 + row) * En + c];
            wp[p] = *(const float4*)&W[(size_t)row * En + c];
        }
    }

    for (int kc = 0; kc < En / 64; ++kc) {
        for (int p = 0; p < 8; ++p) {
            int i = p * 256 + tid, row = i >> 4, c = (i & 15) * 4;
            unsigned short tx[4] = { f2bf(xp[p].x), f2bf(xp[p].y), f2bf(xp[p].z), f2bf(xp[p].w) };
            *(uint2*)&xs[row][c] = *(uint2*)tx;
            unsigned short tw[4] = { f2bf(wp[p].x), f2bf(wp[p].y), f2bf(wp[p].z), f2bf(wp[p].w) };
            *(uint2*)&wsm[row][c] = *(uint2*)tw;
        }
        __syncthreads();
        if (kc + 1 < En / 64) {
            int k0 = (kc + 1) * 64;
            for (int p = 0; p < 8; ++p) {
                int i = p * 256 + tid, row = i >> 4, c = (i & 15) * 4;
                xp[p] = *(const float4*)&x[(size_t)(m0 + row) * En + k0 + c];
                wp[p] = *(const float4*)&W[(size_t)row * En + k0 + c];
            }
        }
        // gy==2: A = W (m-dim = h), B = x (n-dim = s') -> C = v^T
        unsigned short (*As)[72] = (gy == 2) ? wsm : xs;
        unsigned short (*Bs)[72] = (gy == 2) ? xs : wsm;
        for (int kk = 0; kk < 2; ++kk) {
            bf16x8 af[4], bfr[4];
            for (int i = 0; i < 4; ++i) af[i]  = *(const bf16x8*)&As[wm + i * 16 + l15][kk * 32 + quad * 8];
            for (int j = 0; j < 4; ++j) bfr[j] = *(const bf16x8*)&Bs[wn + j * 16 + l15][kk * 32 + quad * 8];
            for (int i = 0; i < 4; ++i)
                for (int j = 0; j < 4; ++j)
                    acc[i][j] = MFMA16(af[i], bfr[j], acc[i][j]);
        }
        __syncthreads();
    }

    // epilogue: C/D layout col=lane&15, row=quad*4+reg
    if (gy != 2) {
        unsigned short* ob = (gy == 0) ? qb : kb;
        for (int i = 0; i < 4; ++i) {
            int rowb = m0 + wm + i * 16 + quad * 4;
            for (int j = 0; j < 4; ++j) {
                int col = wn + j * 16 + l15;
                for (int r = 0; r < 4; ++r)
                    ob[(size_t)(rowb + r) * Hn + col] = f2bf(acc[i][j][r]);
            }
        }
    } else {
        // m-dim = h, n-dim = s' (global x row). vT layout: [b][h][s], s' = b*4096 + s
        for (int i = 0; i < 4; ++i) {
            int hb = wm + i * 16 + quad * 4;
            for (int j = 0; j < 4; ++j) {
                int sp = m0 + wn + j * 16 + l15;
                int bb = sp >> 12, ss = sp & 4095;
                for (int r = 0; r < 4; ++r)
                    vbT[((size_t)(bb * 128 + hb + r)) * Sn + ss] = f2bf(acc[i][j][r]);
            }
        }
    }
}

// ---------------- flash causal attention ----------------
// grid (S/32, B), block 128 (2 waves, each owns 16 q-rows). BQ=32, BK=64.
// K staged natural [key][h]; V staged from precomputed V^T with b128 writes.
__global__ __launch_bounds__(128, 2) void attn_kernel(
    const unsigned short* __restrict__ qb, const unsigned short* __restrict__ kb,
    const unsigned short* __restrict__ vbT, float* __restrict__ out)
{
    __shared__ unsigned short ks[64][136];  // K tile natural [key][h]
    __shared__ unsigned short vt[128][72];  // V^T [h][key]
    __shared__ unsigned short ps[32][72];   // P strip [q][key]

    const int b = blockIdx.y;
    const int qt = (int)gridDim.x - 1 - (int)blockIdx.x;  // longest blocks first
    const int q0 = qt * 32;
    const int tid = threadIdx.x;
    const int lane = tid & 63, wave = tid >> 6;
    const int l15 = lane & 15, quad = lane >> 4;

    const unsigned short* qg = qb + (size_t)(b * Sn + q0) * Hn;
    bf16x8 qf[4];
    {
        int qrow = wave * 16 + l15;
        for (int f = 0; f < 4; ++f)
            qf[f] = *(const bf16x8*)&qg[qrow * Hn + f * 32 + quad * 8];
    }

    f32x4 o[8] = {};
    float m_r[4] = { -INFINITY, -INFINITY, -INFINITY, -INFINITY };
    float l_r[4] = { 0.f, 0.f, 0.f, 0.f };

    const float cscale = 1.44269504089f * 0.03125f;  // log2(e) * E^-0.5
    const int nkt = q0 / 64 + 1;

    const unsigned short* kg = kb + (size_t)b * Sn * Hn;
    const unsigned short* vg = vbT + (size_t)b * 128 * Sn;

    bf16x8 kreg[8], vreg[8];
    for (int p = 0; p < 8; ++p) {
        int i = p * 128 + tid;
        kreg[p] = *(const bf16x8*)&kg[(size_t)(i >> 4) * Hn + (i & 15) * 8];
        vreg[p] = *(const bf16x8*)&vg[(size_t)(i >> 3) * Sn + (i & 7) * 8];
    }

    for (int kt = 0; kt < nkt; ++kt) {
        // stage prefetched tile into LDS (all b128, conflict-light)
        for (int p = 0; p < 8; ++p) {
            int i = p * 128 + tid;
            *(bf16x8*)&ks[i >> 4][(i & 15) * 8] = kreg[p];
            *(bf16x8*)&vt[i >> 3][(i & 7) * 8] = vreg[p];
        }
        __syncthreads();
        if (kt + 1 < nkt) {
            int kt0 = (kt + 1) * 64;
            for (int p = 0; p < 8; ++p) {
                int i = p * 128 + tid;
                kreg[p] = *(const bf16x8*)&kg[(size_t)(kt0 + (i >> 4)) * Hn + (i & 15) * 8];
                vreg[p] = *(const bf16x8*)&vg[(size_t)(i >> 3) * Sn + kt0 + (i & 7) * 8];
            }
        }

        // S = Q K^T (wave: 16 q-rows x 64 keys), log2 domain, E^-0.5 folded in
        float u[4][4];
        for (int nt = 0; nt < 4; ++nt) {
            f32x4 s = {};
            for (int kk = 0; kk < 4; ++kk) {
                bf16x8 kf = *(const bf16x8*)&ks[nt * 16 + l15][kk * 32 + quad * 8];
                s = MFMA16(qf[kk], kf, s);
            }
            for (int r = 0; r < 4; ++r) u[nt][r] = s[r] * cscale;
        }
        if (kt == nkt - 1) {  // causal mask only hits the diagonal tile
            int kt0 = kt * 64;
            for (int nt = 0; nt < 4; ++nt) {
                int key = kt0 + nt * 16 + l15;
                for (int r = 0; r < 4; ++r) {
                    int qq = q0 + wave * 16 + quad * 4 + r;
                    if (key > qq) u[nt][r] = -INFINITY;
                }
            }
        }
        // online softmax: row (quad*4+r) lives on the 16 lanes of this quad
        float alpha[4];
        for (int r = 0; r < 4; ++r) {
            float mx = fmaxf(fmaxf(u[0][r], u[1][r]), fmaxf(u[2][r], u[3][r]));
            for (int d = 1; d < 16; d <<= 1) mx = fmaxf(mx, __shfl_xor(mx, d, 64));
            float mn = fmaxf(m_r[r], mx);
            alpha[r] = exp2f(m_r[r] - mn);
            m_r[r] = mn;
        }
        float rs[4];
        for (int r = 0; r < 4; ++r) {
            float sum = 0.f;
            for (int nt = 0; nt < 4; ++nt) {
                float p = exp2f(u[nt][r] - m_r[r]);
                u[nt][r] = p;
                sum += p;
            }
            rs[r] = sum;
        }
        for (int r = 0; r < 4; ++r) {
            for (int d = 1; d < 16; d <<= 1) rs[r] += __shfl_xor(rs[r], d, 64);
            l_r[r] = l_r[r] * alpha[r] + rs[r];
        }
        // P -> LDS (same-wave strip: no barrier needed before PV reads)
        for (int nt = 0; nt < 4; ++nt)
            for (int r = 0; r < 4; ++r)
                ps[wave * 16 + quad * 4 + r][nt * 16 + l15] = f2bf(u[nt][r]);
        for (int t = 0; t < 8; ++t) {
            f32x4 ot = o[t];
            for (int r = 0; r < 4; ++r) ot[r] *= alpha[r];
            o[t] = ot;
        }
        // O += P V
        for (int k2 = 0; k2 < 2; ++k2) {
            bf16x8 pf = *(const bf16x8*)&ps[wave * 16 + l15][k2 * 32 + quad * 8];
            for (int t = 0; t < 8; ++t) {
                bf16x8 vf = *(const bf16x8*)&vt[t * 16 + l15][k2 * 32 + quad * 8];
                o[t] = MFMA16(pf, vf, o[t]);
            }
        }
        __syncthreads();   // protect ks/vt from next iteration's writes
    }

    float* og = out + (size_t)(b * Sn + q0) * Hn;
    for (int t = 0; t < 8; ++t) {
        for (int r = 0; r < 4; ++r) {
            int row = wave * 16 + quad * 4 + r;
            int col = t * 16 + l15;
            og[(size_t)row * Hn + col] = o[t][r] / l_r[r];
        }
    }
}

extern "C" void kernel_launch(void* const* d_in, const int* in_sizes, int n_in,
                              void* d_out, int out_size, void* d_ws, size_t ws_size,
                              hipStream_t stream)
{
    const float* x  = (const float*)d_in[0];
    const float* Wk = (const float*)d_in[1];
    const float* Wq = (const float*)d_in[2];
    const float* Wv = (const float*)d_in[3];
    float* out = (float*)d_out;

    unsigned short* qbuf  = (unsigned short*)d_ws;                  // 4 MB
    unsigned short* kbuf  = qbuf + (size_t)Bn * Sn * Hn;            // 4 MB
    unsigned short* vbufT = kbuf + (size_t)Bn * Sn * Hn;            // 4 MB, [b][h][s]

    proj_kernel<<<dim3(Bn * Sn / 128, 3), 256, 0, stream>>>(x, Wk, Wq, Wv, qbuf, kbuf, vbufT);
    attn_kernel<<<dim3(Sn / 32, Bn), 128, 0, stream>>>(qbuf, kbuf, vbufT, out);
}

// Round 3
// 267.906 us; speedup vs baseline: 1.8206x; 1.0683x over previous
//
#include <hip/hip_runtime.h>

typedef short bf16x8 __attribute__((ext_vector_type(8)));
typedef float f32x4 __attribute__((ext_vector_type(4)));

#define MFMA16(a, b, c) __builtin_amdgcn_mfma_f32_16x16x32_bf16(a, b, c, 0, 0, 0)

constexpr int Bn = 4, Sn = 4096, En = 1024, Hn = 128;

__device__ inline unsigned short f2bf(float f) {
    unsigned int u = __builtin_bit_cast(unsigned int, f);
    u += 0x7fff + ((u >> 16) & 1);   // round-to-nearest-even
    return (unsigned short)(u >> 16);
}

// ---------------- QKV projection ----------------
// gy 0: q[s][h] = x Wq^T   gy 1: k[s][h] = x Wk^T
// gy 2: vT[h][s] = Wv x^T  (A/B swapped -> output already transposed)
// grid (BS/128, 3), block 256 (4 waves, 2x2 of 64x64 per 128x128 tile). BK=64.
__global__ __launch_bounds__(256, 2) void proj_kernel(
    const float* __restrict__ x,
    const float* __restrict__ Wk, const float* __restrict__ Wq, const float* __restrict__ Wv,
    unsigned short* __restrict__ qb, unsigned short* __restrict__ kb,
    unsigned short* __restrict__ vbT)
{
    __shared__ unsigned short xs[128][72];
    __shared__ unsigned short wsm[128][72];

    const int gy = blockIdx.y;
    const float* W = (gy == 0) ? Wq : (gy == 1) ? Wk : Wv;

    const int m0 = blockIdx.x * 128;
    const int tid = threadIdx.x;
    const int lane = tid & 63, wave = tid >> 6;
    const int l15 = lane & 15, quad = lane >> 4;
    const int wm = (wave & 1) * 64, wn = (wave >> 1) * 64;

    f32x4 acc[4][4] = {};

    float4 xp[8], wp[8];
    for (int p = 0; p < 8; ++p) {
        int i = p * 256 + tid, row = i >> 4, c = (i & 15) * 4;
        xp[p] = *(const float4*)&x[(size_t)(m0 + row) * En + c];
        wp[p] = *(const float4*)&W[(size_t)row * En + c];
    }

    for (int kc = 0; kc < En / 64; ++kc) {
        for (int p = 0; p < 8; ++p) {
            int i = p * 256 + tid, row = i >> 4, c = (i & 15) * 4;
            unsigned short tx[4] = { f2bf(xp[p].x), f2bf(xp[p].y), f2bf(xp[p].z), f2bf(xp[p].w) };
            *(uint2*)&xs[row][c] = *(uint2*)tx;
            unsigned short tw[4] = { f2bf(wp[p].x), f2bf(wp[p].y), f2bf(wp[p].z), f2bf(wp[p].w) };
            *(uint2*)&wsm[row][c] = *(uint2*)tw;
        }
        __syncthreads();
        if (kc + 1 < En / 64) {
            int k0 = (kc + 1) * 64;
            for (int p = 0; p < 8; ++p) {
                int i = p * 256 + tid, row = i >> 4, c = (i & 15) * 4;
                xp[p] = *(const float4*)&x[(size_t)(m0 + row) * En + k0 + c];
                wp[p] = *(const float4*)&W[(size_t)row * En + k0 + c];
            }
        }
        unsigned short (*As)[72] = (gy == 2) ? wsm : xs;
        unsigned short (*Bs)[72] = (gy == 2) ? xs : wsm;
        for (int kk = 0; kk < 2; ++kk) {
            bf16x8 af[4], bfr[4];
            for (int i = 0; i < 4; ++i) af[i]  = *(const bf16x8*)&As[wm + i * 16 + l15][kk * 32 + quad * 8];
            for (int j = 0; j < 4; ++j) bfr[j] = *(const bf16x8*)&Bs[wn + j * 16 + l15][kk * 32 + quad * 8];
            for (int i = 0; i < 4; ++i)
                for (int j = 0; j < 4; ++j)
                    acc[i][j] = MFMA16(af[i], bfr[j], acc[i][j]);
        }
        __syncthreads();
    }

    if (gy != 2) {
        unsigned short* ob = (gy == 0) ? qb : kb;
        for (int i = 0; i < 4; ++i) {
            int rowb = m0 + wm + i * 16 + quad * 4;
            for (int j = 0; j < 4; ++j) {
                int col = wn + j * 16 + l15;
                for (int r = 0; r < 4; ++r)
                    ob[(size_t)(rowb + r) * Hn + col] = f2bf(acc[i][j][r]);
            }
        }
    } else {
        for (int i = 0; i < 4; ++i) {
            int hb = wm + i * 16 + quad * 4;
            for (int j = 0; j < 4; ++j) {
                int sp = m0 + wn + j * 16 + l15;
                int bb = sp >> 12, ss = sp & 4095;
                for (int r = 0; r < 4; ++r)
                    vbT[((size_t)(bb * 128 + hb + r)) * Sn + ss] = f2bf(acc[i][j][r]);
            }
        }
    }
}

// ---------------- flash causal attention (transposed orientation) ----------------
// grid (S/32, B), block 128 (2 waves, each owns 16 q-rows). BQ=32, BK=64.
// S^T = K Q^T  -> C layout: q = lane&15 (in-lane softmax rows), key = quad*4+reg.
// O^T = V^T P^T -> alpha/l are per-lane scalars; epilogue is float4 stores.
__global__ __launch_bounds__(128, 2) void attn_kernel(
    const unsigned short* __restrict__ qb, const unsigned short* __restrict__ kb,
    const unsigned short* __restrict__ vbT, float* __restrict__ out)
{
    __shared__ unsigned short ks[64][136];  // K tile natural [key][h]
    __shared__ unsigned short vt[128][72];  // V^T [h][key]
    __shared__ unsigned short ps[32][72];   // P strip [q][key]

    const int b = blockIdx.y;
    const int qt = (int)gridDim.x - 1 - (int)blockIdx.x;  // longest blocks first
    const int q0 = qt * 32;
    const int tid = threadIdx.x;
    const int lane = tid & 63, wave = tid >> 6;
    const int l15 = lane & 15, quad = lane >> 4;

    // Q fragment: lane(l15=q, quad) holds Q[q0+wave*16+l15][kk*32+quad*8 ..+7]
    // (valid both as A-frag (m=q) and as B-frag (n=q) — we use it as B now)
    const unsigned short* qg = qb + (size_t)(b * Sn + q0) * Hn;
    bf16x8 qf[4];
    {
        int qrow = wave * 16 + l15;
        for (int f = 0; f < 4; ++f)
            qf[f] = *(const bf16x8*)&qg[qrow * Hn + f * 32 + quad * 8];
    }

    f32x4 o[8] = {};             // O^T: col(q)=l15, row(h)=t*16+quad*4+r
    float m_r = -INFINITY;       // per-lane: running max of q-row l15
    float l_r = 0.f;

    const float cscale = 1.44269504089f * 0.03125f;  // log2(e) * E^-0.5
    const int nkt = q0 / 64 + 1;

    const unsigned short* kg = kb + (size_t)b * Sn * Hn;
    const unsigned short* vg = vbT + (size_t)b * 128 * Sn;

    bf16x8 kreg[8], vreg[8];
    for (int p = 0; p < 8; ++p) {
        int i = p * 128 + tid;
        kreg[p] = *(const bf16x8*)&kg[(size_t)(i >> 4) * Hn + (i & 15) * 8];
        vreg[p] = *(const bf16x8*)&vg[(size_t)(i >> 3) * Sn + (i & 7) * 8];
    }

    for (int kt = 0; kt < nkt; ++kt) {
        for (int p = 0; p < 8; ++p) {
            int i = p * 128 + tid;
            *(bf16x8*)&ks[i >> 4][(i & 15) * 8] = kreg[p];
            *(bf16x8*)&vt[i >> 3][(i & 7) * 8] = vreg[p];
        }
        __syncthreads();
        if (kt + 1 < nkt) {
            int kt0n = (kt + 1) * 64;
            for (int p = 0; p < 8; ++p) {
                int i = p * 128 + tid;
                kreg[p] = *(const bf16x8*)&kg[(size_t)(kt0n + (i >> 4)) * Hn + (i & 15) * 8];
                vreg[p] = *(const bf16x8*)&vg[(size_t)(i >> 3) * Sn + kt0n + (i & 7) * 8];
            }
        }

        // S^T tile: A = K (m=key), B = Q (n=q). u[nt][r]: key=kt0+nt*16+quad*4+r, q=l15
        float u[4][4];
        for (int nt = 0; nt < 4; ++nt) {
            f32x4 s = {};
            for (int kk = 0; kk < 4; ++kk) {
                bf16x8 kf = *(const bf16x8*)&ks[nt * 16 + l15][kk * 32 + quad * 8];
                s = MFMA16(kf, qf[kk], s);
            }
            for (int r = 0; r < 4; ++r) u[nt][r] = s[r] * cscale;
        }
        if (kt == nkt - 1) {  // causal mask on diagonal tile
            int kt0 = kt * 64;
            int qq = q0 + wave * 16 + l15;
            for (int nt = 0; nt < 4; ++nt)
                for (int r = 0; r < 4; ++r)
                    if (kt0 + nt * 16 + quad * 4 + r > qq) u[nt][r] = -INFINITY;
        }
        // online softmax: q-row lives on this lane; 16 keys in-lane, rest across quads
        float mx = -INFINITY;
        for (int nt = 0; nt < 4; ++nt)
            for (int r = 0; r < 4; ++r) mx = fmaxf(mx, u[nt][r]);
        mx = fmaxf(mx, __shfl_xor(mx, 16));
        mx = fmaxf(mx, __shfl_xor(mx, 32));
        float mn = fmaxf(m_r, mx);
        float alpha = exp2f(m_r - mn);
        m_r = mn;
        float sum = 0.f;
        for (int nt = 0; nt < 4; ++nt)
            for (int r = 0; r < 4; ++r) {
                float p = exp2f(u[nt][r] - mn);
                u[nt][r] = p;
                sum += p;
            }
        sum += __shfl_xor(sum, 16);
        sum += __shfl_xor(sum, 32);
        l_r = l_r * alpha + sum;

        // P^T -> LDS as P[q][key]: lane writes its 4 contiguous keys per nt (b64)
        for (int nt = 0; nt < 4; ++nt) {
            unsigned short t4[4];
            for (int r = 0; r < 4; ++r) t4[r] = f2bf(u[nt][r]);
            *(uint2*)&ps[wave * 16 + l15][nt * 16 + quad * 4] = *(uint2*)t4;
        }
        for (int t = 0; t < 8; ++t) o[t] *= alpha;

        // O^T += V^T P^T : A = V^T (m=h), B = P (n=q) — same LDS reads as before
        for (int k2 = 0; k2 < 2; ++k2) {
            bf16x8 pf = *(const bf16x8*)&ps[wave * 16 + l15][k2 * 32 + quad * 8];
            for (int t = 0; t < 8; ++t) {
                bf16x8 vf = *(const bf16x8*)&vt[t * 16 + l15][k2 * 32 + quad * 8];
                o[t] = MFMA16(vf, pf, o[t]);
            }
        }
        __syncthreads();   // protect ks/vt from next iteration's writes
    }

    // epilogue: lane owns q-row (q0+wave*16+l15); cols t*16+quad*4..+3 -> float4
    const float inv = 1.0f / l_r;
    float* og = out + (size_t)(b * Sn + q0 + wave * 16 + l15) * Hn;
    for (int t = 0; t < 8; ++t) {
        float4 st = { o[t][0] * inv, o[t][1] * inv, o[t][2] * inv, o[t][3] * inv };
        *(float4*)&og[t * 16 + quad * 4] = st;
    }
}

extern "C" void kernel_launch(void* const* d_in, const int* in_sizes, int n_in,
                              void* d_out, int out_size, void* d_ws, size_t ws_size,
                              hipStream_t stream)
{
    const float* x  = (const float*)d_in[0];
    const float* Wk = (const float*)d_in[1];
    const float* Wq = (const float*)d_in[2];
    const float* Wv = (const float*)d_in[3];
    float* out = (float*)d_out;

    unsigned short* qbuf  = (unsigned short*)d_ws;                  // 4 MB
    unsigned short* kbuf  = qbuf + (size_t)Bn * Sn * Hn;            // 4 MB
    unsigned short* vbufT = kbuf + (size_t)Bn * Sn * Hn;            // 4 MB, [b][h][s]

    proj_kernel<<<dim3(Bn * Sn / 128, 3), 256, 0, stream>>>(x, Wk, Wq, Wv, qbuf, kbuf, vbufT);
    attn_kernel<<<dim3(Sn / 32, Bn), 128, 0, stream>>>(qbuf, kbuf, vbufT, out);
}

// Round 4
// 209.010 us; speedup vs baseline: 2.3336x; 1.2818x over previous
//
#include <hip/hip_runtime.h>

typedef short bf16x8 __attribute__((ext_vector_type(8)));
typedef float f32x4 __attribute__((ext_vector_type(4)));

#define MFMA16(a, b, c) __builtin_amdgcn_mfma_f32_16x16x32_bf16(a, b, c, 0, 0, 0)

constexpr int Bn = 4, Sn = 4096, En = 1024, Hn = 128;

__device__ inline unsigned short f2bf(float f) {
    unsigned int u = __builtin_bit_cast(unsigned int, f);
    u += 0x7fff + ((u >> 16) & 1);   // RTN
    return (unsigned short)(u >> 16);
}

// pack 2 floats -> 2 bf16 (round-to-nearest-away): 2 adds + 1 v_perm
__device__ inline unsigned int pk2(float a, float b) {
    unsigned int ua = __builtin_bit_cast(unsigned int, a) + 0x8000u;
    unsigned int ub = __builtin_bit_cast(unsigned int, b) + 0x8000u;
    return __builtin_amdgcn_perm(ub, ua, 0x07060302u);  // {ub.hi16, ua.hi16}
}

// ---------------- QKV projection ----------------
// 64x128 tiles: grid (BS/64, 3), block 256 (4 waves; wave tile 32x64).
// gy 0: q = x Wq^T   gy 1: k = x Wk^T   gy 2: vT = Wv x^T (A/B swapped)
__global__ __launch_bounds__(256, 2) void proj_kernel(
    const float* __restrict__ x,
    const float* __restrict__ Wk, const float* __restrict__ Wq, const float* __restrict__ Wv,
    unsigned short* __restrict__ qb, unsigned short* __restrict__ kb,
    unsigned short* __restrict__ vbT)
{
    __shared__ unsigned short xs[64][68];     // x k-slice  [s 64][64 bf16 + pad]
    __shared__ unsigned short wsm[128][68];   // W k-slice  [h 128][64 bf16 + pad]

    const int gy = blockIdx.y;
    const float* W = (gy == 0) ? Wq : (gy == 1) ? Wk : Wv;

    const int m0 = blockIdx.x * 64;
    const int tid = threadIdx.x;
    const int lane = tid & 63, wave = tid >> 6;
    const int l15 = lane & 15, quad = lane >> 4;
    const int wm = (wave & 1) * 32;   // s'-tile within 64
    const int wn = (wave >> 1) * 64;  // h-tile within 128

    f32x4 acc[2][4] = {};

    float4 xp[4], wp[8];
    for (int p = 0; p < 4; ++p) {
        int i = p * 256 + tid, row = i >> 4, c = (i & 15) * 4;
        xp[p] = *(const float4*)&x[(size_t)(m0 + row) * En + c];
    }
    for (int p = 0; p < 8; ++p) {
        int i = p * 256 + tid, row = i >> 4, c = (i & 15) * 4;
        wp[p] = *(const float4*)&W[(size_t)row * En + c];
    }

    for (int kc = 0; kc < En / 64; ++kc) {
        for (int p = 0; p < 4; ++p) {
            int i = p * 256 + tid, row = i >> 4, c = (i & 15) * 4;
            uint2 w2 = { pk2(xp[p].x, xp[p].y), pk2(xp[p].z, xp[p].w) };
            *(uint2*)&xs[row][c] = w2;
        }
        for (int p = 0; p < 8; ++p) {
            int i = p * 256 + tid, row = i >> 4, c = (i & 15) * 4;
            uint2 w2 = { pk2(wp[p].x, wp[p].y), pk2(wp[p].z, wp[p].w) };
            *(uint2*)&wsm[row][c] = w2;
        }
        __syncthreads();
        if (kc + 1 < En / 64) {
            int k0 = (kc + 1) * 64;
            for (int p = 0; p < 4; ++p) {
                int i = p * 256 + tid, row = i >> 4, c = (i & 15) * 4;
                xp[p] = *(const float4*)&x[(size_t)(m0 + row) * En + k0 + c];
            }
            for (int p = 0; p < 8; ++p) {
                int i = p * 256 + tid, row = i >> 4, c = (i & 15) * 4;
                wp[p] = *(const float4*)&W[(size_t)row * En + k0 + c];
            }
        }
        if (gy != 2) {
            for (int kk = 0; kk < 2; ++kk) {
                bf16x8 af[2], bfr[4];
                for (int i = 0; i < 2; ++i) af[i]  = *(const bf16x8*)&xs[wm + i * 16 + l15][kk * 32 + quad * 8];
                for (int j = 0; j < 4; ++j) bfr[j] = *(const bf16x8*)&wsm[wn + j * 16 + l15][kk * 32 + quad * 8];
                for (int i = 0; i < 2; ++i)
                    for (int j = 0; j < 4; ++j)
                        acc[i][j] = MFMA16(af[i], bfr[j], acc[i][j]);
            }
        } else {
            // A = W (m=h), B = x (n=s') -> C = v^T
            for (int kk = 0; kk < 2; ++kk) {
                bf16x8 aw[4], bx[2];
                for (int j = 0; j < 4; ++j) aw[j] = *(const bf16x8*)&wsm[wn + j * 16 + l15][kk * 32 + quad * 8];
                for (int i = 0; i < 2; ++i) bx[i] = *(const bf16x8*)&xs[wm + i * 16 + l15][kk * 32 + quad * 8];
                for (int i = 0; i < 2; ++i)
                    for (int j = 0; j < 4; ++j)
                        acc[i][j] = MFMA16(aw[j], bx[i], acc[i][j]);
            }
        }
        __syncthreads();
    }

    if (gy != 2) {
        unsigned short* ob = (gy == 0) ? qb : kb;
        for (int i = 0; i < 2; ++i) {
            int rowb = m0 + wm + i * 16 + quad * 4;
            for (int j = 0; j < 4; ++j) {
                int col = wn + j * 16 + l15;
                for (int r = 0; r < 4; ++r)
                    ob[(size_t)(rowb + r) * Hn + col] = f2bf(acc[i][j][r]);
            }
        }
    } else {
        // C[h][s']: row(m)=h = wn + j*16 + quad*4 + r, col(n)=s' = m0 + wm + i*16 + l15
        for (int j = 0; j < 4; ++j) {
            int hb = wn + j * 16 + quad * 4;
            for (int i = 0; i < 2; ++i) {
                int sp = m0 + wm + i * 16 + l15;
                int bb = sp >> 12, ss = sp & 4095;
                for (int r = 0; r < 4; ++r)
                    vbT[((size_t)(bb * 128 + hb + r)) * Sn + ss] = f2bf(acc[i][j][r]);
            }
        }
    }
}

// ---------------- flash causal attention, in-block 2-way K-split ----------------
// grid (S/32, B), block 256 = 4 waves = 2 pairs. Pair p handles k-tiles 2i+p with
// private LDS tiles; wave g of a pair owns q-rows g*16..+15. S^T=K Q^T orientation
// (q on lane&15 -> per-lane online softmax, 2 shuffles). LDS merge of the 2 partials.
__global__ __launch_bounds__(256, 2) void attn_kernel(
    const unsigned short* __restrict__ qb, const unsigned short* __restrict__ kb,
    const unsigned short* __restrict__ vbT, float* __restrict__ out)
{
    __shared__ unsigned short ks[2][64][132];  // per-pair K tile [key][h]
    __shared__ unsigned short vt[2][128][68];  // per-pair V^T [h][key]
    __shared__ unsigned short ps[2][32][68];   // per-pair P [q][key]

    const int b = blockIdx.y;
    const int qt = (int)gridDim.x - 1 - (int)blockIdx.x;  // longest blocks first
    const int q0 = qt * 32;
    const int tid = threadIdx.x;
    const int lane = tid & 63, wave = tid >> 6;
    const int l15 = lane & 15, quad = lane >> 4;
    const int g = wave & 1;       // q-row group
    const int p = wave >> 1;      // k-split
    const int tpp = tid & 127;    // thread-in-pair

    const unsigned short* qg = qb + (size_t)(b * Sn + q0) * Hn;
    bf16x8 qf[4];
    {
        int qrow = g * 16 + l15;
        for (int f = 0; f < 4; ++f)
            qf[f] = *(const bf16x8*)&qg[qrow * Hn + f * 32 + quad * 8];
    }

    f32x4 o[8] = {};          // O^T partial: h = t*16+quad*4+r, q = l15
    float m_r = -INFINITY, l_r = 0.f;

    const float cscale = 1.44269504089f * 0.03125f;  // log2(e) * E^-0.5
    const int nkt = q0 / 64 + 1;
    const int ni = (nkt + 1) >> 1;

    const unsigned short* kg = kb + (size_t)b * Sn * Hn;
    const unsigned short* vg = vbT + (size_t)b * 128 * Sn;

    bf16x8 kreg[8], vreg[8];
    {
        int kt0 = p * 64;   // in-bounds even if unused
        for (int p8 = 0; p8 < 8; ++p8) {
            int i = p8 * 128 + tpp;
            kreg[p8] = *(const bf16x8*)&kg[(size_t)(kt0 + (i >> 4)) * Hn + (i & 15) * 8];
            vreg[p8] = *(const bf16x8*)&vg[(size_t)(i >> 3) * Sn + kt0 + (i & 7) * 8];
        }
    }

    for (int it = 0; it < ni; ++it) {
        const int kt = 2 * it + p;
        const bool active = kt < nkt;
        for (int p8 = 0; p8 < 8; ++p8) {
            int i = p8 * 128 + tpp;
            *(bf16x8*)&ks[p][i >> 4][(i & 15) * 8] = kreg[p8];
            *(bf16x8*)&vt[p][i >> 3][(i & 7) * 8] = vreg[p8];
        }
        __syncthreads();
        if (kt + 2 < nkt) {
            int kt0n = (kt + 2) * 64;
            for (int p8 = 0; p8 < 8; ++p8) {
                int i = p8 * 128 + tpp;
                kreg[p8] = *(const bf16x8*)&kg[(size_t)(kt0n + (i >> 4)) * Hn + (i & 15) * 8];
                vreg[p8] = *(const bf16x8*)&vg[(size_t)(i >> 3) * Sn + kt0n + (i & 7) * 8];
            }
        }
        if (active) {
            // S^T: A = K (m=key), B = Q (n=q). u[nt][r]: key = kt*64+nt*16+quad*4+r, q=l15
            float u[4][4];
            for (int nt = 0; nt < 4; ++nt) {
                f32x4 s = {};
                for (int kk = 0; kk < 4; ++kk) {
                    bf16x8 kf = *(const bf16x8*)&ks[p][nt * 16 + l15][kk * 32 + quad * 8];
                    s = MFMA16(kf, qf[kk], s);
                }
                for (int r = 0; r < 4; ++r) u[nt][r] = s[r] * cscale;
            }
            if (kt == nkt - 1) {  // causal mask (diagonal tile only)
                int kt0 = kt * 64;
                int qq = q0 + g * 16 + l15;
                for (int nt = 0; nt < 4; ++nt)
                    for (int r = 0; r < 4; ++r)
                        if (kt0 + nt * 16 + quad * 4 + r > qq) u[nt][r] = -INFINITY;
            }
            // per-lane online softmax (q-row on this lane; 16 keys in-lane)
            float mx = -INFINITY;
            for (int nt = 0; nt < 4; ++nt)
                for (int r = 0; r < 4; ++r) mx = fmaxf(mx, u[nt][r]);
            mx = fmaxf(mx, __shfl_xor(mx, 16));
            mx = fmaxf(mx, __shfl_xor(mx, 32));
            float mn = fmaxf(m_r, mx);
            float alpha = exp2f(m_r - mn);
            m_r = mn;
            float sum = 0.f;
            for (int nt = 0; nt < 4; ++nt)
                for (int r = 0; r < 4; ++r) {
                    float pv = exp2f(u[nt][r] - mn);
                    u[nt][r] = pv;
                    sum += pv;
                }
            sum += __shfl_xor(sum, 16);
            sum += __shfl_xor(sum, 32);
            l_r = l_r * alpha + sum;

            for (int nt = 0; nt < 4; ++nt) {
                uint2 w2 = { pk2(u[nt][0], u[nt][1]), pk2(u[nt][2], u[nt][3]) };
                *(uint2*)&ps[p][g * 16 + l15][nt * 16 + quad * 4] = w2;
            }
            for (int t = 0; t < 8; ++t) o[t] *= alpha;

            // O^T += V^T P^T (ps strip is same-wave: no barrier needed)
            for (int k2 = 0; k2 < 2; ++k2) {
                bf16x8 pf = *(const bf16x8*)&ps[p][g * 16 + l15][k2 * 32 + quad * 8];
                for (int t = 0; t < 8; ++t) {
                    bf16x8 vf = *(const bf16x8*)&vt[p][t * 16 + l15][k2 * 32 + quad * 8];
                    o[t] = MFMA16(vf, pf, o[t]);
                }
            }
        }
        __syncthreads();
    }

    // ---- merge the two k-split partials (LDS overlay on ks/vt) ----
    float* mo = (float*)&ks[0][0][0];   // [2][128][17] f32
    float* ml = (float*)&vt[0][0][0];   // [2][{m,l}][16] f32
    if (p == 1) {
        for (int t = 0; t < 8; ++t)
            for (int r = 0; r < 4; ++r)
                mo[(size_t)(g * 128 + t * 16 + quad * 4 + r) * 17 + l15] = o[t][r];
        if (quad == 0) {
            ml[g * 32 + l15] = m_r;
            ml[g * 32 + 16 + l15] = l_r;
        }
    }
    __syncthreads();
    if (p == 0) {
        float m1 = ml[g * 32 + l15];
        float l1 = ml[g * 32 + 16 + l15];
        float M = fmaxf(m_r, m1);
        float w0 = exp2f(m_r - M);
        float w1 = exp2f(m1 - M);
        float L = w0 * l_r + w1 * l1;
        float inv = 1.0f / L;
        float* og = out + (size_t)(b * Sn + q0 + g * 16 + l15) * Hn;
        for (int t = 0; t < 8; ++t) {
            float4 st;
            float* mor = &mo[(size_t)(g * 128 + t * 16 + quad * 4) * 17 + l15];
            st.x = (w0 * o[t][0] + w1 * mor[0 * 17]) * inv;
            st.y = (w0 * o[t][1] + w1 * mor[1 * 17]) * inv;
            st.z = (w0 * o[t][2] + w1 * mor[2 * 17]) * inv;
            st.w = (w0 * o[t][3] + w1 * mor[3 * 17]) * inv;
            *(float4*)&og[t * 16 + quad * 4] = st;
        }
    }
}

extern "C" void kernel_launch(void* const* d_in, const int* in_sizes, int n_in,
                              void* d_out, int out_size, void* d_ws, size_t ws_size,
                              hipStream_t stream)
{
    const float* x  = (const float*)d_in[0];
    const float* Wk = (const float*)d_in[1];
    const float* Wq = (const float*)d_in[2];
    const float* Wv = (const float*)d_in[3];
    float* out = (float*)d_out;

    unsigned short* qbuf  = (unsigned short*)d_ws;                  // 4 MB
    unsigned short* kbuf  = qbuf + (size_t)Bn * Sn * Hn;            // 4 MB
    unsigned short* vbufT = kbuf + (size_t)Bn * Sn * Hn;            // 4 MB, [b][h][s]

    proj_kernel<<<dim3(Bn * Sn / 64, 3), 256, 0, stream>>>(x, Wk, Wq, Wv, qbuf, kbuf, vbufT);
    attn_kernel<<<dim3(Sn / 32, Bn), 256, 0, stream>>>(qbuf, kbuf, vbufT, out);
}